// Round 7
// baseline (206.299 us; speedup 1.0000x reference)
//
#include <hip/hip_runtime.h>
#include <hip/hip_bf16.h>
#include <stdint.h>

#define B_TOTAL 131072

typedef __attribute__((ext_vector_type(8))) short short8;
typedef __attribute__((ext_vector_type(4))) float float4v;

// ===== fragment-linear ws layout (16x16x32 MFMA decomposition) =====
// Per chamber (u16 units):
//   F1: 32 frags (nt*4+kb, nt=0..7, kb=0..3) x 64 lanes x 8 bf16 -> 16384 u16 (32 KB)
//       k-slot (l>>4)*8+e, K padded 100->128 (kb=3 mostly zero)
//   F2: 16 frags (nt2*4+kb) x 64 x 8 -> 8192 u16 (16 KB), k PERMUTED (see below)
//   F3:  4 frags (nt3*2+kb) x 64 x 8 -> 2048 u16 ( 4 KB), k PERMUTED
// Permuted k for F2/F3: slot (q4=l>>4, e) holds k = kb*32 + 16*(e>>2) + 4*q4 + (e&3),
// matching the D-layout of the previous layer so the next B-frag is 4 of the
// lane's own pk registers — no cross-lane shuffles anywhere.
#define CH_U16 26624
#define oF2 16384
#define oF3 24576
#define BF16_TOT (6 * CH_U16)          // 159744 u16
#define F32_BASE (BF16_TOT / 2)        // 79872 floats
// f32 smalls, element offsets (also used inside sB):
#define sB1 0
#define sB2 768
#define sB3 1152
#define sW4 1344
#define sB4 1536
#define sCP 1542
#define sDC 1578
#define NSMALL 1584
#define CONV_TOT (BF16_TOT + NSMALL)

#define GLB_AS __attribute__((address_space(1)))
#define LDS_AS __attribute__((address_space(3)))

__device__ __forceinline__ float bf16_as_f32(uint16_t u) {
    union { uint32_t i; float f; } v; v.i = ((uint32_t)u) << 16; return v.f;
}
__device__ __forceinline__ uint16_t f2bf(float f) {
    uint32_t u = __float_as_uint(f);
    return (uint16_t)((u + 0x7FFFu + ((u >> 16) & 1u)) >> 16);   // RNE
}
__device__ __forceinline__ float sigmoidf_fast(float x) {
    return __builtin_amdgcn_rcpf(1.0f + __expf(-x));
}
__device__ __forceinline__ float siluf(float x) { return x * sigmoidf_fast(x); }

__device__ __forceinline__ float readsrc(const void* p, int off, bool bf) {
    return bf ? bf16_as_f32(((const uint16_t*)p)[off]) : ((const float*)p)[off];
}

__device__ __forceinline__ uint32_t cvtpk_bf16(float lo, float hi) {
    uint32_t r;
    asm("v_cvt_pk_bf16_f32 %0, %1, %2" : "=v"(r) : "v"(lo), "v"(hi));
    return r;
}
__device__ __forceinline__ uint32_t silu2bf(float a, float b) {
    return cvtpk_bf16(siluf(a), siluf(b));    // known-good scalar path
}

// Fragment-linear bf16 weights + f32 smalls, 16x16x32 layout.
__global__ void convert_kernel(const void* W1, const void* b1, const void* W2, const void* b2,
                               const void* W3, const void* b3, const void* W4, const void* b4,
                               const void* cp, const void* dc, uint16_t* __restrict__ wsb) {
    const bool bf = (((const uint32_t*)cp)[0] != 0u);
    int idx = blockIdx.x * 256 + threadIdx.x;
    if (idx >= CONV_TOT) return;
    if (idx < BF16_TOT) {
        int c = idx / CH_U16;
        int r = idx - c * CH_U16;
        float v;
        if (r < oF2) {                       // F1: standard k-slots, pad 100->128
            int f = r >> 9, rem = r & 511, l = rem >> 3, e = rem & 7;
            int nt = f >> 2, kb = f & 3;
            int n = nt * 16 + (l & 15);
            int k = kb * 32 + (l >> 4) * 8 + e;
            v = (k < 100) ? readsrc(W1, c * 12800 + k * 128 + n, bf) : 0.0f;
        } else if (r < oF3) {                // F2: PERMUTED k-slots
            int j = r - oF2;
            int f = j >> 9, rem = j & 511, l = rem >> 3, e = rem & 7;
            int nt2 = f >> 2, kb = f & 3;
            int n = nt2 * 16 + (l & 15);
            int k = kb * 32 + 16 * (e >> 2) + 4 * (l >> 4) + (e & 3);
            v = readsrc(W2, c * 8192 + k * 64 + n, bf);
        } else {                             // F3: PERMUTED k-slots
            int j = r - oF3;
            int f = j >> 9, rem = j & 511, l = rem >> 3, e = rem & 7;
            int nt3 = f >> 1, kb = f & 1;
            int n = nt3 * 16 + (l & 15);
            int k = kb * 32 + 16 * (e >> 2) + 4 * (l >> 4) + (e & 3);
            v = readsrc(W3, c * 2048 + k * 32 + n, bf);
        }
        wsb[idx] = f2bf(v);
    } else {
        int fi = idx - BF16_TOT;
        float v;
        if      (fi < sB2)  v = readsrc(b1, fi, bf);
        else if (fi < sB3)  v = readsrc(b2, fi - sB2, bf);
        else if (fi < sW4)  v = readsrc(b3, fi - sB3, bf);
        else if (fi < sB4)  v = readsrc(W4, fi - sW4, bf);
        else if (fi < sCP)  v = readsrc(b4, fi - sB4, bf);
        else if (fi < sDC)  v = readsrc(cp, fi - sCP, bf);
        else                v = readsrc(dc, fi - sDC, bf);
        ((float*)wsb)[F32_BASE + fi] = v;
    }
}

union Frag { uint4 u4; uint2 u2[2]; uint32_t u[4]; short8 s8; uint16_t h[8]; };

// 16x16x32 transposed-MFMA chain: each wave owns 16 batch rows (4 lanes/row)
// -> 8192 waves = 32 waves/CU = 8/SIMD (2x round-6 occupancy). A = weights
// (F1 from LDS; F2/F3 streamed from global, k-permuted), B = activations in
// registers. Inter-layer handoff needs ZERO shuffles: B-frag(kb) = the lane's
// own {pk[2kb][0],pk[2kb][1],pk[2kb+1][0],pk[2kb+1][1]}. Bias folded into
// MFMA C-in. 512 thr = 8 waves x 16 rows = 128 rows/block, grid 1024;
// LDS 39.1 KB -> 4 blocks/CU.
__global__ __launch_bounds__(512, 8)
void chambers_mfma(const void* __restrict__ resv, const uint16_t* __restrict__ wsb,
                   const uint32_t* __restrict__ cpw, float* __restrict__ outF) {
    const float* wsf = (const float*)wsb;
    const bool bfin = (cpw[0] != 0u);
    const int tid = threadIdx.x;
    const int w = tid >> 6, l = tid & 63;
    const int r4 = l & 15, q4 = l >> 4;
    const int row = blockIdx.x * 128 + w * 16 + r4;

    __shared__ __align__(16) uint16_t sW[16384];   // 32 KB: F1 of current chamber
    __shared__ __align__(16) float sB[NSMALL];     // 6336 B biases/consts

#define STAGE(CC)                                                              \
    {                                                                          \
        const uint16_t* gsrc = wsb + (CC) * CH_U16;                            \
        _Pragma("unroll")                                                      \
        for (int rr = 0; rr < 4; ++rr) {                                       \
            const int i = rr * 8 + w;              /* chunk 0..31, 1 KB */     \
            __builtin_amdgcn_global_load_lds(                                  \
                (const GLB_AS uint32_t*)(gsrc + i * 512 + l * 8),              \
                (LDS_AS uint32_t*)(sW + i * 512), 16, 0, 0);                   \
        }                                                                      \
    }

    STAGE(0)
    for (int i = tid; i < NSMALL; i += 512) sB[i] = wsf[F32_BASE + i];

    // ===== res row fragments (B operand): k = kb*32 + q4*8 + e, K 100->128 =====
    Frag R[3], R3;
    R3.u4 = make_uint4(0, 0, 0, 0);
    if (bfin) {
        const uint16_t* bp = (const uint16_t*)resv + (size_t)row * 100;
#pragma unroll
        for (int kb = 0; kb < 3; ++kb) {
            const int k0 = kb * 32 + q4 * 8;
            R[kb].u2[0] = *(const uint2*)(bp + k0);
            R[kb].u2[1] = *(const uint2*)(bp + k0 + 4);
        }
        if (q4 == 0) R3.u2[0] = *(const uint2*)(bp + 96);   // k 96..99
    } else {
        const float* fp = (const float*)resv + (size_t)row * 100;
#pragma unroll
        for (int kb = 0; kb < 3; ++kb) {
            const int k0 = kb * 32 + q4 * 8;
            float4 x0 = *(const float4*)(fp + k0);
            float4 x1 = *(const float4*)(fp + k0 + 4);
            R[kb].u[0] = cvtpk_bf16(x0.x, x0.y);
            R[kb].u[1] = cvtpk_bf16(x0.z, x0.w);
            R[kb].u[2] = cvtpk_bf16(x1.x, x1.y);
            R[kb].u[3] = cvtpk_bf16(x1.z, x1.w);
        }
        if (q4 == 0) {
            float4 x0 = *(const float4*)(fp + 96);
            R3.u[0] = cvtpk_bf16(x0.x, x0.y);
            R3.u[1] = cvtpk_bf16(x0.z, x0.w);
        }
    }

    __syncthreads();               // stage 0 + sB visible

    float raw0 = 0.f, raw1 = 0.f, raw2 = 0.f, raw3 = 0.f, raw4 = 0.f, raw5 = 0.f;
    uint32_t pk1[8][2];            // H1 (n=128): 16 u32, static-indexed
    uint32_t pk2[4][2];            // H2 (n=64)

#pragma unroll 1
    for (int c = 0; c < 6; ++c) {
        // ===== L1: H1^T = W1 . res^T  (8 n-tiles of 16, K=128 padded) =====
#pragma unroll
        for (int nt = 0; nt < 8; ++nt) {
            float4v acc;
            {   // bias-fold: C-in = b1[n], n = nt*16 + q4*4 + reg
                const float4 bv = *(const float4*)(sB + sB1 + c * 128 + nt * 16 + q4 * 4);
                acc[0] = bv.x; acc[1] = bv.y; acc[2] = bv.z; acc[3] = bv.w;
            }
            const uint16_t* fp1 = sW + (nt * 4) * 512 + l * 8;
            Frag A0, A1, A2, A3;
            A0.u4 = *(const uint4*)(fp1);
            A1.u4 = *(const uint4*)(fp1 + 512);
            A2.u4 = *(const uint4*)(fp1 + 1024);
            A3.u4 = *(const uint4*)(fp1 + 1536);
            acc = __builtin_amdgcn_mfma_f32_16x16x32_bf16(A0.s8, R[0].s8, acc, 0, 0, 0);
            acc = __builtin_amdgcn_mfma_f32_16x16x32_bf16(A1.s8, R[1].s8, acc, 0, 0, 0);
            acc = __builtin_amdgcn_mfma_f32_16x16x32_bf16(A2.s8, R[2].s8, acc, 0, 0, 0);
            acc = __builtin_amdgcn_mfma_f32_16x16x32_bf16(A3.s8, R3.s8,   acc, 0, 0, 0);
            pk1[nt][0] = silu2bf(acc[0], acc[1]);
            pk1[nt][1] = silu2bf(acc[2], acc[3]);
        }

        // ===== L2: H2^T = W2 . H1^T  (4 n-tiles, K=128; F2 global, k-permuted) =====
        const uint16_t* gF2 = wsb + c * CH_U16 + oF2;
#pragma unroll
        for (int nt2 = 0; nt2 < 4; ++nt2) {
            float4v acc;
            {
                const float4 bv = *(const float4*)(sB + sB2 + c * 64 + nt2 * 16 + q4 * 4);
                acc[0] = bv.x; acc[1] = bv.y; acc[2] = bv.z; acc[3] = bv.w;
            }
#pragma unroll
            for (int kb = 0; kb < 4; ++kb) {
                Frag Hf;
                Hf.u[0] = pk1[2 * kb][0];     Hf.u[1] = pk1[2 * kb][1];
                Hf.u[2] = pk1[2 * kb + 1][0]; Hf.u[3] = pk1[2 * kb + 1][1];
                Frag Af; Af.u4 = *(const uint4*)(gF2 + ((nt2 * 4 + kb) * 64 + l) * 8);
                acc = __builtin_amdgcn_mfma_f32_16x16x32_bf16(Af.s8, Hf.s8, acc, 0, 0, 0);
            }
            pk2[nt2][0] = silu2bf(acc[0], acc[1]);
            pk2[nt2][1] = silu2bf(acc[2], acc[3]);
        }

        // ===== L3+L4: H3^T = W3 . H2^T (2 n-tiles, K=64) -> raw partial =====
        const uint16_t* gF3 = wsb + c * CH_U16 + oF3;
        float part = 0.f;
#pragma unroll
        for (int nt3 = 0; nt3 < 2; ++nt3) {
            float4v acc;
            {
                const float4 bv = *(const float4*)(sB + sB3 + c * 32 + nt3 * 16 + q4 * 4);
                acc[0] = bv.x; acc[1] = bv.y; acc[2] = bv.z; acc[3] = bv.w;
            }
#pragma unroll
            for (int kb = 0; kb < 2; ++kb) {
                Frag Hf;
                Hf.u[0] = pk2[2 * kb][0];     Hf.u[1] = pk2[2 * kb][1];
                Hf.u[2] = pk2[2 * kb + 1][0]; Hf.u[3] = pk2[2 * kb + 1][1];
                Frag Af; Af.u4 = *(const uint4*)(gF3 + ((nt3 * 2 + kb) * 64 + l) * 8);
                acc = __builtin_amdgcn_mfma_f32_16x16x32_bf16(Af.s8, Hf.s8, acc, 0, 0, 0);
            }
            const float4 wv = *(const float4*)(sB + sW4 + c * 32 + nt3 * 16 + q4 * 4);
            part = fmaf(siluf(acc[0]), wv.x, part);
            part = fmaf(siluf(acc[1]), wv.y, part);
            part = fmaf(siluf(acc[2]), wv.z, part);
            part = fmaf(siluf(acc[3]), wv.w, part);
        }
        part += __shfl_xor(part, 16);      // reduce over the 4 lanes sharing r4
        part += __shfl_xor(part, 32);
        const float rv = part + sB[sB4 + c];
        raw0 = (c == 0) ? rv : raw0;
        raw1 = (c == 1) ? rv : raw1;
        raw2 = (c == 2) ? rv : raw2;
        raw3 = (c == 3) ? rv : raw3;
        raw4 = (c == 4) ? rv : raw4;
        raw5 = (c == 5) ? rv : raw5;

        if (c < 5) {
            __syncthreads();               // all waves done reading sW (chamber c)
            STAGE(c + 1)
            __syncthreads();               // chamber c+1 staged
        }
    }

    // ===== Coupling fixed point (redundant over q4; static indexing) =====
    const float rv6[6] = {raw0, raw1, raw2, raw3, raw4, raw5};
    float av[6];
#pragma unroll
    for (int c = 0; c < 6; ++c) av[c] = sigmoidf_fast(rv6[c]);
    const float K = 0.02f;
#pragma unroll 1
    for (int it = 0; it < 5; ++it) {
        float tt[6];
#pragma unroll
        for (int i = 0; i < 6; ++i) tt[i] = av[i] * sB[sDC + i] * K;
#pragma unroll
        for (int j = 0; j < 6; ++j) {
            float dl = 0.0f;
#pragma unroll
            for (int i = 0; i < 6; ++i) dl = fmaf(tt[i], sB[sCP + i * 6 + j], dl);
            av[j] = sigmoidf_fast(rv6[j] + dl);
        }
    }
    if (q4 == 0) {
        float2* oa = (float2*)(outF + (size_t)row * 6);
        oa[0] = make_float2(av[0], av[1]);
        oa[1] = make_float2(av[2], av[3]);
        oa[2] = make_float2(av[4], av[5]);
        float2* orw = (float2*)(outF + (size_t)B_TOTAL * 6 + (size_t)row * 6);
        orw[0] = make_float2(rv6[0], rv6[1]);
        orw[1] = make_float2(rv6[2], rv6[3]);
        orw[2] = make_float2(rv6[4], rv6[5]);
    }
#undef STAGE
}

extern "C" void kernel_launch(void* const* d_in, const int* in_sizes, int n_in,
                              void* d_out, int out_size, void* d_ws, size_t ws_size,
                              hipStream_t stream) {
    uint16_t* wsb = (uint16_t*)d_ws;
    convert_kernel<<<(CONV_TOT + 255) / 256, 256, 0, stream>>>(
        d_in[1], d_in[2], d_in[3], d_in[4], d_in[5], d_in[6], d_in[7], d_in[8],
        d_in[9], d_in[10], wsb);
    chambers_mfma<<<B_TOTAL / 128, 512, 0, stream>>>(
        d_in[0], wsb, (const uint32_t*)d_in[9], (float*)d_out);
}

// Round 8
// 169.902 us; speedup vs baseline: 1.2142x; 1.2142x over previous
//
#include <hip/hip_runtime.h>
#include <hip/hip_bf16.h>
#include <stdint.h>

#define B_TOTAL 131072

typedef __attribute__((ext_vector_type(8))) short short8;
typedef __attribute__((ext_vector_type(4))) float float4v;

// ===== fragment-linear ws layout (16x16x32 MFMA decomposition) =====
// Per chamber (u16 units):
//   F1: 32 frags (nt*4+kb, nt=0..7, kb=0..3) x 64 lanes x 8 bf16 -> 16384 u16 (32 KB)
//       k-slot (l>>4)*8+e, K padded 100->128 (kb=3 mostly zero)
//   F2: 16 frags (nt2*4+kb) x 64 x 8 -> 8192 u16 (16 KB), k PERMUTED (see below)
//   F3:  4 frags (nt3*2+kb) x 64 x 8 -> 2048 u16 ( 4 KB), k PERMUTED
// Permuted k for F2/F3: slot (q4=l>>4, e) holds k = kb*32 + 16*(e>>2) + 4*q4 + (e&3),
// matching the D-layout of the previous layer so the next B-frag is 4 of the
// lane's own pk registers — no cross-lane shuffles anywhere.
#define CH_U16 26624
#define oF2 16384
#define oF3 24576
#define BF16_TOT (6 * CH_U16)          // 159744 u16
#define F32_BASE (BF16_TOT / 2)        // 79872 floats
// f32 smalls, element offsets (also used inside sB):
#define sB1 0
#define sB2 768
#define sB3 1152
#define sW4 1344
#define sB4 1536
#define sCP 1542
#define sDC 1578
#define NSMALL 1584
#define CONV_TOT (BF16_TOT + NSMALL)

#define GLB_AS __attribute__((address_space(1)))
#define LDS_AS __attribute__((address_space(3)))

__device__ __forceinline__ float bf16_as_f32(uint16_t u) {
    union { uint32_t i; float f; } v; v.i = ((uint32_t)u) << 16; return v.f;
}
__device__ __forceinline__ uint16_t f2bf(float f) {
    uint32_t u = __float_as_uint(f);
    return (uint16_t)((u + 0x7FFFu + ((u >> 16) & 1u)) >> 16);   // RNE
}
__device__ __forceinline__ float sigmoidf_fast(float x) {
    return __builtin_amdgcn_rcpf(1.0f + __expf(-x));
}
__device__ __forceinline__ float siluf(float x) { return x * sigmoidf_fast(x); }

__device__ __forceinline__ float readsrc(const void* p, int off, bool bf) {
    return bf ? bf16_as_f32(((const uint16_t*)p)[off]) : ((const float*)p)[off];
}

__device__ __forceinline__ uint32_t cvtpk_bf16(float lo, float hi) {
    uint32_t r;
    asm("v_cvt_pk_bf16_f32 %0, %1, %2" : "=v"(r) : "v"(lo), "v"(hi));
    return r;
}
__device__ __forceinline__ uint32_t silu2bf(float a, float b) {
    return cvtpk_bf16(siluf(a), siluf(b));    // known-good scalar path
}

// Fragment-linear bf16 weights + f32 smalls, 16x16x32 layout. (verified round 7)
__global__ void convert_kernel(const void* W1, const void* b1, const void* W2, const void* b2,
                               const void* W3, const void* b3, const void* W4, const void* b4,
                               const void* cp, const void* dc, uint16_t* __restrict__ wsb) {
    const bool bf = (((const uint32_t*)cp)[0] != 0u);
    int idx = blockIdx.x * 256 + threadIdx.x;
    if (idx >= CONV_TOT) return;
    if (idx < BF16_TOT) {
        int c = idx / CH_U16;
        int r = idx - c * CH_U16;
        float v;
        if (r < oF2) {                       // F1: standard k-slots, pad 100->128
            int f = r >> 9, rem = r & 511, l = rem >> 3, e = rem & 7;
            int nt = f >> 2, kb = f & 3;
            int n = nt * 16 + (l & 15);
            int k = kb * 32 + (l >> 4) * 8 + e;
            v = (k < 100) ? readsrc(W1, c * 12800 + k * 128 + n, bf) : 0.0f;
        } else if (r < oF3) {                // F2: PERMUTED k-slots
            int j = r - oF2;
            int f = j >> 9, rem = j & 511, l = rem >> 3, e = rem & 7;
            int nt2 = f >> 2, kb = f & 3;
            int n = nt2 * 16 + (l & 15);
            int k = kb * 32 + 16 * (e >> 2) + 4 * (l >> 4) + (e & 3);
            v = readsrc(W2, c * 8192 + k * 64 + n, bf);
        } else {                             // F3: PERMUTED k-slots
            int j = r - oF3;
            int f = j >> 9, rem = j & 511, l = rem >> 3, e = rem & 7;
            int nt3 = f >> 1, kb = f & 1;
            int n = nt3 * 16 + (l & 15);
            int k = kb * 32 + 16 * (e >> 2) + 4 * (l >> 4) + (e & 3);
            v = readsrc(W3, c * 2048 + k * 32 + n, bf);
        }
        wsb[idx] = f2bf(v);
    } else {
        int fi = idx - BF16_TOT;
        float v;
        if      (fi < sB2)  v = readsrc(b1, fi, bf);
        else if (fi < sB3)  v = readsrc(b2, fi - sB2, bf);
        else if (fi < sW4)  v = readsrc(b3, fi - sB3, bf);
        else if (fi < sB4)  v = readsrc(W4, fi - sW4, bf);
        else if (fi < sCP)  v = readsrc(b4, fi - sB4, bf);
        else if (fi < sDC)  v = readsrc(cp, fi - sCP, bf);
        else                v = readsrc(dc, fi - sDC, bf);
        ((float*)wsb)[F32_BASE + fi] = v;
    }
}

union Frag { uint4 u4; uint2 u2[2]; uint32_t u[4]; short8 s8; uint16_t h[8]; };

// 16x16x32 transposed-MFMA chain: each wave owns 16 batch rows (4 lanes/row).
// Round-8 change vs round 7: __launch_bounds__(512, 6) — 85 VGPR/wave budget
// (live set ~78) instead of 64 (which spilled ~190 MB to scratch, r7 evidence:
// VGPR=32, WRITE_SIZE 105 MB). 6 waves/SIMD = 24 waves/CU = 1.5x round-6 supply.
// A = weights (F1 from LDS; F2/F3 streamed from global, k-permuted), B =
// activations in registers; zero-shuffle layer handoff; bias folded into C-in.
// 512 thr = 8 waves x 16 rows = 128 rows/block, grid 1024; LDS 39.1 KB.
__global__ __launch_bounds__(512, 6)
void chambers_mfma(const void* __restrict__ resv, const uint16_t* __restrict__ wsb,
                   const uint32_t* __restrict__ cpw, float* __restrict__ outF) {
    const float* wsf = (const float*)wsb;
    const bool bfin = (cpw[0] != 0u);
    const int tid = threadIdx.x;
    const int w = tid >> 6, l = tid & 63;
    const int r4 = l & 15, q4 = l >> 4;
    const int row = blockIdx.x * 128 + w * 16 + r4;

    __shared__ __align__(16) uint16_t sW[16384];   // 32 KB: F1 of current chamber
    __shared__ __align__(16) float sB[NSMALL];     // 6336 B biases/consts

#define STAGE(CC)                                                              \
    {                                                                          \
        const uint16_t* gsrc = wsb + (CC) * CH_U16;                            \
        _Pragma("unroll")                                                      \
        for (int rr = 0; rr < 4; ++rr) {                                       \
            const int i = rr * 8 + w;              /* chunk 0..31, 1 KB */     \
            __builtin_amdgcn_global_load_lds(                                  \
                (const GLB_AS uint32_t*)(gsrc + i * 512 + l * 8),              \
                (LDS_AS uint32_t*)(sW + i * 512), 16, 0, 0);                   \
        }                                                                      \
    }

    STAGE(0)
    for (int i = tid; i < NSMALL; i += 512) sB[i] = wsf[F32_BASE + i];

    // ===== res row fragments (B operand): k = kb*32 + q4*8 + e, K 100->128 =====
    Frag R[3], R3;
    R3.u4 = make_uint4(0, 0, 0, 0);
    if (bfin) {
        const uint16_t* bp = (const uint16_t*)resv + (size_t)row * 100;
#pragma unroll
        for (int kb = 0; kb < 3; ++kb) {
            const int k0 = kb * 32 + q4 * 8;
            R[kb].u2[0] = *(const uint2*)(bp + k0);
            R[kb].u2[1] = *(const uint2*)(bp + k0 + 4);
        }
        if (q4 == 0) R3.u2[0] = *(const uint2*)(bp + 96);   // k 96..99
    } else {
        const float* fp = (const float*)resv + (size_t)row * 100;
#pragma unroll
        for (int kb = 0; kb < 3; ++kb) {
            const int k0 = kb * 32 + q4 * 8;
            float4 x0 = *(const float4*)(fp + k0);
            float4 x1 = *(const float4*)(fp + k0 + 4);
            R[kb].u[0] = cvtpk_bf16(x0.x, x0.y);
            R[kb].u[1] = cvtpk_bf16(x0.z, x0.w);
            R[kb].u[2] = cvtpk_bf16(x1.x, x1.y);
            R[kb].u[3] = cvtpk_bf16(x1.z, x1.w);
        }
        if (q4 == 0) {
            float4 x0 = *(const float4*)(fp + 96);
            R3.u[0] = cvtpk_bf16(x0.x, x0.y);
            R3.u[1] = cvtpk_bf16(x0.z, x0.w);
        }
    }

    __syncthreads();               // stage 0 + sB visible

    float raw0 = 0.f, raw1 = 0.f, raw2 = 0.f, raw3 = 0.f, raw4 = 0.f, raw5 = 0.f;
    uint32_t pk1[8][2];            // H1 (n=128): 16 u32, static-indexed
    uint32_t pk2[4][2];            // H2 (n=64)

#pragma unroll 1
    for (int c = 0; c < 6; ++c) {
        // ===== L1: H1^T = W1 . res^T  (8 n-tiles of 16, K=128 padded) =====
#pragma unroll
        for (int nt = 0; nt < 8; ++nt) {
            float4v acc;
            {   // bias-fold: C-in = b1[n], n = nt*16 + q4*4 + reg
                const float4 bv = *(const float4*)(sB + sB1 + c * 128 + nt * 16 + q4 * 4);
                acc[0] = bv.x; acc[1] = bv.y; acc[2] = bv.z; acc[3] = bv.w;
            }
            const uint16_t* fp1 = sW + (nt * 4) * 512 + l * 8;
            Frag A0, A1, A2, A3;
            A0.u4 = *(const uint4*)(fp1);
            A1.u4 = *(const uint4*)(fp1 + 512);
            A2.u4 = *(const uint4*)(fp1 + 1024);
            A3.u4 = *(const uint4*)(fp1 + 1536);
            acc = __builtin_amdgcn_mfma_f32_16x16x32_bf16(A0.s8, R[0].s8, acc, 0, 0, 0);
            acc = __builtin_amdgcn_mfma_f32_16x16x32_bf16(A1.s8, R[1].s8, acc, 0, 0, 0);
            acc = __builtin_amdgcn_mfma_f32_16x16x32_bf16(A2.s8, R[2].s8, acc, 0, 0, 0);
            acc = __builtin_amdgcn_mfma_f32_16x16x32_bf16(A3.s8, R3.s8,   acc, 0, 0, 0);
            pk1[nt][0] = silu2bf(acc[0], acc[1]);
            pk1[nt][1] = silu2bf(acc[2], acc[3]);
        }

        // ===== L2: H2^T = W2 . H1^T  (4 n-tiles, K=128; F2 global, k-permuted) =====
        const uint16_t* gF2 = wsb + c * CH_U16 + oF2;
#pragma unroll
        for (int nt2 = 0; nt2 < 4; ++nt2) {
            float4v acc;
            {
                const float4 bv = *(const float4*)(sB + sB2 + c * 64 + nt2 * 16 + q4 * 4);
                acc[0] = bv.x; acc[1] = bv.y; acc[2] = bv.z; acc[3] = bv.w;
            }
#pragma unroll
            for (int kb = 0; kb < 4; ++kb) {
                Frag Hf;
                Hf.u[0] = pk1[2 * kb][0];     Hf.u[1] = pk1[2 * kb][1];
                Hf.u[2] = pk1[2 * kb + 1][0]; Hf.u[3] = pk1[2 * kb + 1][1];
                Frag Af; Af.u4 = *(const uint4*)(gF2 + ((nt2 * 4 + kb) * 64 + l) * 8);
                acc = __builtin_amdgcn_mfma_f32_16x16x32_bf16(Af.s8, Hf.s8, acc, 0, 0, 0);
            }
            pk2[nt2][0] = silu2bf(acc[0], acc[1]);
            pk2[nt2][1] = silu2bf(acc[2], acc[3]);
        }

        // ===== L3+L4: H3^T = W3 . H2^T (2 n-tiles, K=64) -> raw partial =====
        const uint16_t* gF3 = wsb + c * CH_U16 + oF3;
        float part = 0.f;
#pragma unroll
        for (int nt3 = 0; nt3 < 2; ++nt3) {
            float4v acc;
            {
                const float4 bv = *(const float4*)(sB + sB3 + c * 32 + nt3 * 16 + q4 * 4);
                acc[0] = bv.x; acc[1] = bv.y; acc[2] = bv.z; acc[3] = bv.w;
            }
#pragma unroll
            for (int kb = 0; kb < 2; ++kb) {
                Frag Hf;
                Hf.u[0] = pk2[2 * kb][0];     Hf.u[1] = pk2[2 * kb][1];
                Hf.u[2] = pk2[2 * kb + 1][0]; Hf.u[3] = pk2[2 * kb + 1][1];
                Frag Af; Af.u4 = *(const uint4*)(gF3 + ((nt3 * 2 + kb) * 64 + l) * 8);
                acc = __builtin_amdgcn_mfma_f32_16x16x32_bf16(Af.s8, Hf.s8, acc, 0, 0, 0);
            }
            const float4 wv = *(const float4*)(sB + sW4 + c * 32 + nt3 * 16 + q4 * 4);
            part = fmaf(siluf(acc[0]), wv.x, part);
            part = fmaf(siluf(acc[1]), wv.y, part);
            part = fmaf(siluf(acc[2]), wv.z, part);
            part = fmaf(siluf(acc[3]), wv.w, part);
        }
        part += __shfl_xor(part, 16);      // reduce over the 4 lanes sharing r4
        part += __shfl_xor(part, 32);
        const float rv = part + sB[sB4 + c];
        raw0 = (c == 0) ? rv : raw0;
        raw1 = (c == 1) ? rv : raw1;
        raw2 = (c == 2) ? rv : raw2;
        raw3 = (c == 3) ? rv : raw3;
        raw4 = (c == 4) ? rv : raw4;
        raw5 = (c == 5) ? rv : raw5;

        if (c < 5) {
            __syncthreads();               // all waves done reading sW (chamber c)
            STAGE(c + 1)
            __syncthreads();               // chamber c+1 staged
        }
    }

    // ===== Coupling fixed point (redundant over q4; static indexing) =====
    const float rv6[6] = {raw0, raw1, raw2, raw3, raw4, raw5};
    float av[6];
#pragma unroll
    for (int c = 0; c < 6; ++c) av[c] = sigmoidf_fast(rv6[c]);
    const float K = 0.02f;
#pragma unroll 1
    for (int it = 0; it < 5; ++it) {
        float tt[6];
#pragma unroll
        for (int i = 0; i < 6; ++i) tt[i] = av[i] * sB[sDC + i] * K;
#pragma unroll
        for (int j = 0; j < 6; ++j) {
            float dl = 0.0f;
#pragma unroll
            for (int i = 0; i < 6; ++i) dl = fmaf(tt[i], sB[sCP + i * 6 + j], dl);
            av[j] = sigmoidf_fast(rv6[j] + dl);
        }
    }
    if (q4 == 0) {
        float2* oa = (float2*)(outF + (size_t)row * 6);
        oa[0] = make_float2(av[0], av[1]);
        oa[1] = make_float2(av[2], av[3]);
        oa[2] = make_float2(av[4], av[5]);
        float2* orw = (float2*)(outF + (size_t)B_TOTAL * 6 + (size_t)row * 6);
        orw[0] = make_float2(rv6[0], rv6[1]);
        orw[1] = make_float2(rv6[2], rv6[3]);
        orw[2] = make_float2(rv6[4], rv6[5]);
    }
#undef STAGE
}

extern "C" void kernel_launch(void* const* d_in, const int* in_sizes, int n_in,
                              void* d_out, int out_size, void* d_ws, size_t ws_size,
                              hipStream_t stream) {
    uint16_t* wsb = (uint16_t*)d_ws;
    convert_kernel<<<(CONV_TOT + 255) / 256, 256, 0, stream>>>(
        d_in[1], d_in[2], d_in[3], d_in[4], d_in[5], d_in[6], d_in[7], d_in[8],
        d_in[9], d_in[10], wsb);
    chambers_mfma<<<B_TOTAL / 128, 512, 0, stream>>>(
        d_in[0], wsb, (const uint32_t*)d_in[9], (float*)d_out);
}

// Round 9
// 164.492 us; speedup vs baseline: 1.2542x; 1.0329x over previous
//
#include <hip/hip_runtime.h>
#include <hip/hip_bf16.h>
#include <stdint.h>

#define B_TOTAL 131072

typedef __attribute__((ext_vector_type(8))) short short8;
typedef __attribute__((ext_vector_type(16))) float float16v;

// ===== fragment-linear ws layout (32x32x16, k-PERMUTED F2/F3) =====
// Per chamber (u16 units):
//   F1: 28 frags (ct*7+kb) x 64 lanes x 8 bf16 -> 14336 u16 (28 KB)
//       n = ct*32+(l&31), k = kb*16 + (l>>5)*8 + e  (k>=100 -> 0)
//   F2: 16 frags (ct2*8+kb) x 64 x 8 -> 8192 u16 (16 KB), k PERMUTED:
//       n = ct2*32+(l&31), k = 32(kb>>1) + 8(e>>1) + 4(l>>5) + 2(kb&1) + (e&1)
//   F3:  4 frags (kb) x 64 x 8 -> 2048 u16 (4 KB), same k-permute, n = l&31
// The permute matches the 32x32 D-layout (n = 32ct + 8(i>>2) + 4q2 + (i&3)) so
// the next layer's B-frag kb is EXACTLY the lane's own packed quad
// pk1f[kb&1][kb>>1] — zero shuffles, zero repack movs.
#define CH_U16 24576
#define oF2 14336
#define oF3 22528
#define BF16_TOT (6 * CH_U16)          // 147456 u16
#define F32_BASE (BF16_TOT / 2)        // 73728 floats
// f32 smalls, element offsets (also used inside sB):
#define sB1 0
#define sB2 768
#define sB3 1152
#define sW4 1344
#define sB4 1536
#define sCP 1542
#define sDC 1578
#define NSMALL 1584
#define CONV_TOT (BF16_TOT + NSMALL)

#define GLB_AS __attribute__((address_space(1)))
#define LDS_AS __attribute__((address_space(3)))

__device__ __forceinline__ float bf16_as_f32(uint16_t u) {
    union { uint32_t i; float f; } v; v.i = ((uint32_t)u) << 16; return v.f;
}
__device__ __forceinline__ uint16_t f2bf(float f) {
    uint32_t u = __float_as_uint(f);
    return (uint16_t)((u + 0x7FFFu + ((u >> 16) & 1u)) >> 16);   // RNE
}
__device__ __forceinline__ float sigmoidf_fast(float x) {
    return __builtin_amdgcn_rcpf(1.0f + __expf(-x));
}
__device__ __forceinline__ float siluf(float x) { return x * sigmoidf_fast(x); }

__device__ __forceinline__ float readsrc(const void* p, int off, bool bf) {
    return bf ? bf16_as_f32(((const uint16_t*)p)[off]) : ((const float*)p)[off];
}

__device__ __forceinline__ uint32_t cvtpk_bf16(float lo, float hi) {
    uint32_t r;
    asm("v_cvt_pk_bf16_f32 %0, %1, %2" : "=v"(r) : "v"(lo), "v"(hi));
    return r;
}
__device__ __forceinline__ uint32_t silu2bf(float a, float b) {
    return cvtpk_bf16(siluf(a), siluf(b));    // known-good scalar path
}

// Fragment-linear bf16 weights + f32 smalls, 32x32 layout with k-permuted F2/F3.
__global__ void convert_kernel(const void* W1, const void* b1, const void* W2, const void* b2,
                               const void* W3, const void* b3, const void* W4, const void* b4,
                               const void* cp, const void* dc, uint16_t* __restrict__ wsb) {
    const bool bf = (((const uint32_t*)cp)[0] != 0u);
    int idx = blockIdx.x * 256 + threadIdx.x;
    if (idx >= CONV_TOT) return;
    if (idx < BF16_TOT) {
        int c = idx / CH_U16;
        int r = idx - c * CH_U16;
        float v;
        if (r < oF2) {                       // F1: standard k-slots, pad 100->112
            int f = r >> 9, rem = r & 511, l = rem >> 3, e = rem & 7;
            int ct = f / 7, kb = f - ct * 7;
            int n = ct * 32 + (l & 31), k = kb * 16 + (l >> 5) * 8 + e;
            v = (k < 100) ? readsrc(W1, c * 12800 + k * 128 + n, bf) : 0.0f;
        } else if (r < oF3) {                // F2: PERMUTED k-slots
            int j = r - oF2;
            int f = j >> 9, rem = j & 511, l = rem >> 3, e = rem & 7;
            int ct2 = f >> 3, kb = f & 7;
            int n = ct2 * 32 + (l & 31);
            int k = 32 * (kb >> 1) + 8 * (e >> 1) + 4 * (l >> 5) + 2 * (kb & 1) + (e & 1);
            v = readsrc(W2, c * 8192 + k * 64 + n, bf);
        } else {                             // F3: PERMUTED k-slots
            int j = r - oF3;
            int kb = j >> 9, rem = j & 511, l = rem >> 3, e = rem & 7;
            int n = (l & 31);
            int k = 32 * (kb >> 1) + 8 * (e >> 1) + 4 * (l >> 5) + 2 * (kb & 1) + (e & 1);
            v = readsrc(W3, c * 2048 + k * 32 + n, bf);
        }
        wsb[idx] = f2bf(v);
    } else {
        int fi = idx - BF16_TOT;
        float v;
        if      (fi < sB2)  v = readsrc(b1, fi, bf);
        else if (fi < sB3)  v = readsrc(b2, fi - sB2, bf);
        else if (fi < sW4)  v = readsrc(b3, fi - sB3, bf);
        else if (fi < sB4)  v = readsrc(W4, fi - sW4, bf);
        else if (fi < sCP)  v = readsrc(b4, fi - sB4, bf);
        else if (fi < sDC)  v = readsrc(cp, fi - sCP, bf);
        else                v = readsrc(dc, fi - sDC, bf);
        ((float*)wsb)[F32_BASE + fi] = v;
    }
}

union Frag { uint4 u4; uint2 u2[2]; uint32_t u[4]; short8 s8; uint16_t h[8]; };

#define Z16 {0.f,0.f,0.f,0.f,0.f,0.f,0.f,0.f,0.f,0.f,0.f,0.f,0.f,0.f,0.f,0.f}

// 32x32x16 transposed-MFMA chain with ZERO-SHUFFLE layer handoff:
// D-layout (n = 32ct + 8(i>>2) + 4q2 + (i&3)) packed as
//   pk1f[j][ct].u[ar] = cvtpk(acc[4ar+2j], acc[4ar+2j+1])
// and F2/F3 k-permuted to k = 32(kb>>1)+8(e>>1)+4q2+2(kb&1)+(e&1), so the
// L2/L3 B-frag for kb is pk1f[kb&1][kb>>1] — the lane's own contiguous quad.
// All weights in LDS (48 KB single buffer, imm-offset ds_read_b128); biases
// folded into MFMA C-in. 512 thr = 8 waves x 32 rows = 256 rows/block,
// grid 512; LDS 55.5 KB -> 2 blocks/CU (16 waves/CU, r6's proven occupancy).
__global__ __launch_bounds__(512, 4)
void chambers_mfma(const void* __restrict__ resv, const uint16_t* __restrict__ wsb,
                   const uint32_t* __restrict__ cpw, float* __restrict__ outF) {
    const float* wsf = (const float*)wsb;
    const bool bfin = (cpw[0] != 0u);
    const int tid = threadIdx.x;
    const int w = tid >> 6, l = tid & 63;
    const int l5 = l & 31, q2 = l >> 5;
    const int row = blockIdx.x * 256 + w * 32 + l5;

    __shared__ __align__(16) uint16_t sW[CH_U16];  // 48 KB: F1+F2+F3, one chamber
    __shared__ __align__(16) float sB[NSMALL];     // 6336 B biases/consts

#define STAGE(CC)                                                              \
    {                                                                          \
        const uint16_t* gsrc = wsb + (CC) * CH_U16;                            \
        _Pragma("unroll")                                                      \
        for (int rr = 0; rr < 6; ++rr) {                                       \
            const int i = rr * 8 + w;              /* chunk 0..47, 1 KB */     \
            __builtin_amdgcn_global_load_lds(                                  \
                (const GLB_AS uint32_t*)(gsrc + i * 512 + l * 8),              \
                (LDS_AS uint32_t*)(sW + i * 512), 16, 0, 0);                   \
        }                                                                      \
    }

    STAGE(0)
    for (int i = tid; i < NSMALL; i += 512) sB[i] = wsf[F32_BASE + i];

    // ===== res row fragments (B operand): k = kb*16 + q2*8 + e, K 100->112 =====
    Frag R[7];
    if (bfin) {
        const uint16_t* bp = (const uint16_t*)resv + (size_t)row * 100;
#pragma unroll
        for (int kb = 0; kb < 6; ++kb) {
            const int k0 = kb * 16 + q2 * 8;
            R[kb].u2[0] = *(const uint2*)(bp + k0);
            R[kb].u2[1] = *(const uint2*)(bp + k0 + 4);
        }
        R[6].u4 = make_uint4(0, 0, 0, 0);
        if (q2 == 0) R[6].u2[0] = *(const uint2*)(bp + 96);
    } else {
        const float* fp = (const float*)resv + (size_t)row * 100;
#pragma unroll
        for (int kb = 0; kb < 6; ++kb) {
            const int k0 = kb * 16 + q2 * 8;
            float4 x0 = *(const float4*)(fp + k0);
            float4 x1 = *(const float4*)(fp + k0 + 4);
            R[kb].u[0] = cvtpk_bf16(x0.x, x0.y);
            R[kb].u[1] = cvtpk_bf16(x0.z, x0.w);
            R[kb].u[2] = cvtpk_bf16(x1.x, x1.y);
            R[kb].u[3] = cvtpk_bf16(x1.z, x1.w);
        }
        R[6].u4 = make_uint4(0, 0, 0, 0);
        if (q2 == 0) {
            float4 x0 = *(const float4*)(fp + 96);
            R[6].u[0] = cvtpk_bf16(x0.x, x0.y);
            R[6].u[1] = cvtpk_bf16(x0.z, x0.w);
        }
    }

    __syncthreads();               // stage 0 + sB visible

    float raw0 = 0.f, raw1 = 0.f, raw2 = 0.f, raw3 = 0.f, raw4 = 0.f, raw5 = 0.f;
    Frag pk1f[2][4];               // H1: [j][ct], u[ar] — static-indexed
    Frag pk2f[2][2];               // H2: [j][ct2]

#pragma unroll 1
    for (int c = 0; c < 6; ++c) {
        // ===== L1: H1^T = W1 . res^T  (4 col-tiles of 32, K=112) =====
#pragma unroll
        for (int ct = 0; ct < 4; ++ct) {
            float16v acc;
#pragma unroll
            for (int ar = 0; ar < 4; ++ar) {           // bias-fold: C-in = b1
                const float4 bv = *(const float4*)(sB + sB1 + c * 128 + ct * 32 + ar * 8 + q2 * 4);
                acc[4 * ar + 0] = bv.x; acc[4 * ar + 1] = bv.y;
                acc[4 * ar + 2] = bv.z; acc[4 * ar + 3] = bv.w;
            }
            const uint16_t* fp1 = sW + (ct * 7) * 512 + l * 8;
#pragma unroll
            for (int kb = 0; kb < 7; ++kb) {
                Frag Af; Af.u4 = *(const uint4*)(fp1 + kb * 512);
                acc = __builtin_amdgcn_mfma_f32_32x32x16_bf16(Af.s8, R[kb].s8, acc, 0, 0, 0);
            }
#pragma unroll
            for (int ar = 0; ar < 4; ++ar) {
                pk1f[0][ct].u[ar] = silu2bf(acc[4 * ar + 0], acc[4 * ar + 1]);
                pk1f[1][ct].u[ar] = silu2bf(acc[4 * ar + 2], acc[4 * ar + 3]);
            }
        }

        // ===== L2: H2^T = W2 . H1^T  (2 col-tiles, K=128; zero-shuffle B) =====
#pragma unroll
        for (int ct2 = 0; ct2 < 2; ++ct2) {
            float16v acc;
#pragma unroll
            for (int ar = 0; ar < 4; ++ar) {           // bias-fold: C-in = b2
                const float4 bv = *(const float4*)(sB + sB2 + c * 64 + ct2 * 32 + ar * 8 + q2 * 4);
                acc[4 * ar + 0] = bv.x; acc[4 * ar + 1] = bv.y;
                acc[4 * ar + 2] = bv.z; acc[4 * ar + 3] = bv.w;
            }
            const uint16_t* fp2 = sW + oF2 + (ct2 * 8) * 512 + l * 8;
#pragma unroll
            for (int kb = 0; kb < 8; ++kb) {
                Frag Af; Af.u4 = *(const uint4*)(fp2 + kb * 512);
                acc = __builtin_amdgcn_mfma_f32_32x32x16_bf16(Af.s8, pk1f[kb & 1][kb >> 1].s8, acc, 0, 0, 0);
            }
#pragma unroll
            for (int ar = 0; ar < 4; ++ar) {
                pk2f[0][ct2].u[ar] = silu2bf(acc[4 * ar + 0], acc[4 * ar + 1]);
                pk2f[1][ct2].u[ar] = silu2bf(acc[4 * ar + 2], acc[4 * ar + 3]);
            }
        }

        // ===== L3: H3^T = W3 . H2^T  (1 col-tile of 32, K=64; zero-shuffle B) =====
        {
            float16v acc;
#pragma unroll
            for (int ar = 0; ar < 4; ++ar) {           // bias-fold: C-in = b3
                const float4 bv = *(const float4*)(sB + sB3 + c * 32 + ar * 8 + q2 * 4);
                acc[4 * ar + 0] = bv.x; acc[4 * ar + 1] = bv.y;
                acc[4 * ar + 2] = bv.z; acc[4 * ar + 3] = bv.w;
            }
            const uint16_t* fp3 = sW + oF3 + l * 8;
#pragma unroll
            for (int kb = 0; kb < 4; ++kb) {
                Frag Af; Af.u4 = *(const uint4*)(fp3 + kb * 512);
                acc = __builtin_amdgcn_mfma_f32_32x32x16_bf16(Af.s8, pk2f[kb & 1][kb >> 1].s8, acc, 0, 0, 0);
            }
            // ===== L4: raw[r=l5] = silu(H3).W4 + b4, reduce over q2 =====
            float part = 0.f;
#pragma unroll
            for (int ar = 0; ar < 4; ++ar) {
                const float4 wv = *(const float4*)(sB + sW4 + c * 32 + ar * 8 + q2 * 4);
                part = fmaf(siluf(acc[4 * ar + 0]), wv.x, part);
                part = fmaf(siluf(acc[4 * ar + 1]), wv.y, part);
                part = fmaf(siluf(acc[4 * ar + 2]), wv.z, part);
                part = fmaf(siluf(acc[4 * ar + 3]), wv.w, part);
            }
            part += __shfl_xor(part, 32);
            const float rv = part + sB[sB4 + c];
            raw0 = (c == 0) ? rv : raw0;
            raw1 = (c == 1) ? rv : raw1;
            raw2 = (c == 2) ? rv : raw2;
            raw3 = (c == 3) ? rv : raw3;
            raw4 = (c == 4) ? rv : raw4;
            raw5 = (c == 5) ? rv : raw5;
        }

        if (c < 5) {
            __syncthreads();               // all waves done reading sW (chamber c)
            STAGE(c + 1)
            __syncthreads();               // chamber c+1 staged
        }
    }

    // ===== Coupling fixed point (redundant over q2; static indexing) =====
    const float rv6[6] = {raw0, raw1, raw2, raw3, raw4, raw5};
    float av[6];
#pragma unroll
    for (int c = 0; c < 6; ++c) av[c] = sigmoidf_fast(rv6[c]);
    const float K = 0.02f;
#pragma unroll 1
    for (int it = 0; it < 5; ++it) {
        float tt[6];
#pragma unroll
        for (int i = 0; i < 6; ++i) tt[i] = av[i] * sB[sDC + i] * K;
#pragma unroll
        for (int j = 0; j < 6; ++j) {
            float dl = 0.0f;
#pragma unroll
            for (int i = 0; i < 6; ++i) dl = fmaf(tt[i], sB[sCP + i * 6 + j], dl);
            av[j] = sigmoidf_fast(rv6[j] + dl);
        }
    }
    if (q2 == 0) {
        float2* oa = (float2*)(outF + (size_t)row * 6);
        oa[0] = make_float2(av[0], av[1]);
        oa[1] = make_float2(av[2], av[3]);
        oa[2] = make_float2(av[4], av[5]);
        float2* orw = (float2*)(outF + (size_t)B_TOTAL * 6 + (size_t)row * 6);
        orw[0] = make_float2(rv6[0], rv6[1]);
        orw[1] = make_float2(rv6[2], rv6[3]);
        orw[2] = make_float2(rv6[4], rv6[5]);
    }
#undef STAGE
}

extern "C" void kernel_launch(void* const* d_in, const int* in_sizes, int n_in,
                              void* d_out, int out_size, void* d_ws, size_t ws_size,
                              hipStream_t stream) {
    uint16_t* wsb = (uint16_t*)d_ws;
    convert_kernel<<<(CONV_TOT + 255) / 256, 256, 0, stream>>>(
        d_in[1], d_in[2], d_in[3], d_in[4], d_in[5], d_in[6], d_in[7], d_in[8],
        d_in[9], d_in[10], wsb);
    chambers_mfma<<<B_TOTAL / 256, 512, 0, stream>>>(
        d_in[0], wsb, (const uint32_t*)d_in[9], (float*)d_out);
}

// Round 11
// 159.207 us; speedup vs baseline: 1.2958x; 1.0332x over previous
//
#include <hip/hip_runtime.h>
#include <hip/hip_bf16.h>
#include <stdint.h>

#define B_TOTAL 131072

typedef __attribute__((ext_vector_type(8))) short short8;
typedef __attribute__((ext_vector_type(16))) float float16v;
typedef __attribute__((ext_vector_type(2))) float f32x2;

// ===== fragment-linear ws layout (32x32x16, k-PERMUTED F2/F3) =====
// Per chamber (u16 units):
//   F1: 28 frags (ct*7+kb) x 64 lanes x 8 bf16 -> 14336 u16 (28 KB)
//       n = ct*32+(l&31), k = kb*16 + (l>>5)*8 + e  (k>=100 -> 0)
//   F2: 16 frags (ct2*8+kb) x 64 x 8 -> 8192 u16 (16 KB), k PERMUTED:
//       n = ct2*32+(l&31), k = 32(kb>>1) + 8(e>>1) + 4(l>>5) + 2(kb&1) + (e&1)
//   F3:  4 frags (kb) x 64 x 8 -> 2048 u16 (4 KB), same k-permute, n = l&31
// The permute matches the 32x32 D-layout (n = 32ct + 8(i>>2) + 4q2 + (i&3)) so
// the next layer's B-frag kb is EXACTLY the lane's own packed quad
// pk1f[kb&1][kb>>1] — zero shuffles, zero repack movs. (verified round 9)
#define CH_U16 24576
#define oF2 14336
#define oF3 22528
#define BF16_TOT (6 * CH_U16)          // 147456 u16
#define F32_BASE (BF16_TOT / 2)        // 73728 floats
// f32 smalls, element offsets (also used inside sB):
#define sB1 0
#define sB2 768
#define sB3 1152
#define sW4 1344
#define sB4 1536
#define sCP 1542
#define sDC 1578
#define NSMALL 1584
#define CONV_TOT (BF16_TOT + NSMALL)

#define GLB_AS __attribute__((address_space(1)))
#define LDS_AS __attribute__((address_space(3)))

__device__ __forceinline__ float bf16_as_f32(uint16_t u) {
    union { uint32_t i; float f; } v; v.i = ((uint32_t)u) << 16; return v.f;
}
__device__ __forceinline__ uint16_t f2bf(float f) {
    uint32_t u = __float_as_uint(f);
    return (uint16_t)((u + 0x7FFFu + ((u >> 16) & 1u)) >> 16);   // RNE
}
__device__ __forceinline__ float sigmoidf_fast(float x) {
    return __builtin_amdgcn_rcpf(1.0f + __expf(-x));
}
__device__ __forceinline__ float siluf(float x) { return x * sigmoidf_fast(x); }

__device__ __forceinline__ float readsrc(const void* p, int off, bool bf) {
    return bf ? bf16_as_f32(((const uint16_t*)p)[off]) : ((const float*)p)[off];
}

__device__ __forceinline__ uint32_t cvtpk_bf16(float lo, float hi) {
    uint32_t r;
    asm("v_cvt_pk_bf16_f32 %0, %1, %2" : "=v"(r) : "v"(lo), "v"(hi));
    return r;
}

// ---- round-11 silu pair: pure C, NO pk-asm (r4/r10 NaN culprit retired) ----
// (1) ext_vector <2 x float> ops let the backend select v_pk_add/mul_f32
//     natively (worst case scalarizes == round-9 codegen).
// (2) shared-rcp: sigma(a)=(1+e^-b)*rcp((1+e^-a)(1+e^-b)), sigma(b) symm. —
//     trades one 8-cyc trans for three 2-cyc muls per pair. Safe: exp
//     overflow needs |x|>88; preactivations here are O(1).
__device__ __forceinline__ uint32_t silu2bf(float a, float b) {
    float ea = __expf(-a), eb = __expf(-b);
    f32x2 e; e.x = ea; e.y = eb;
    f32x2 one; one.x = 1.0f; one.y = 1.0f;
    f32x2 d = e + one;                         // v_pk_add_f32 (or 2x v_add)
    float p = d.x * d.y;
    float rp = __builtin_amdgcn_rcpf(p);
    f32x2 s; s.x = d.y * rp; s.y = d.x * rp;   // sigmoid(a), sigmoid(b)
    f32x2 x; x.x = a; x.y = b;
    f32x2 o = x * s;                           // v_pk_mul_f32 (or 2x v_mul)
    return cvtpk_bf16(o.x, o.y);
}

// Fragment-linear bf16 weights + f32 smalls, 32x32 layout with k-permuted F2/F3.
// (unchanged, verified round 9)
__global__ void convert_kernel(const void* W1, const void* b1, const void* W2, const void* b2,
                               const void* W3, const void* b3, const void* W4, const void* b4,
                               const void* cp, const void* dc, uint16_t* __restrict__ wsb) {
    const bool bf = (((const uint32_t*)cp)[0] != 0u);
    int idx = blockIdx.x * 256 + threadIdx.x;
    if (idx >= CONV_TOT) return;
    if (idx < BF16_TOT) {
        int c = idx / CH_U16;
        int r = idx - c * CH_U16;
        float v;
        if (r < oF2) {                       // F1: standard k-slots, pad 100->112
            int f = r >> 9, rem = r & 511, l = rem >> 3, e = rem & 7;
            int ct = f / 7, kb = f - ct * 7;
            int n = ct * 32 + (l & 31), k = kb * 16 + (l >> 5) * 8 + e;
            v = (k < 100) ? readsrc(W1, c * 12800 + k * 128 + n, bf) : 0.0f;
        } else if (r < oF3) {                // F2: PERMUTED k-slots
            int j = r - oF2;
            int f = j >> 9, rem = j & 511, l = rem >> 3, e = rem & 7;
            int ct2 = f >> 3, kb = f & 7;
            int n = ct2 * 32 + (l & 31);
            int k = 32 * (kb >> 1) + 8 * (e >> 1) + 4 * (l >> 5) + 2 * (kb & 1) + (e & 1);
            v = readsrc(W2, c * 8192 + k * 64 + n, bf);
        } else {                             // F3: PERMUTED k-slots
            int j = r - oF3;
            int kb = j >> 9, rem = j & 511, l = rem >> 3, e = rem & 7;
            int n = (l & 31);
            int k = 32 * (kb >> 1) + 8 * (e >> 1) + 4 * (l >> 5) + 2 * (kb & 1) + (e & 1);
            v = readsrc(W3, c * 2048 + k * 32 + n, bf);
        }
        wsb[idx] = f2bf(v);
    } else {
        int fi = idx - BF16_TOT;
        float v;
        if      (fi < sB2)  v = readsrc(b1, fi, bf);
        else if (fi < sB3)  v = readsrc(b2, fi - sB2, bf);
        else if (fi < sW4)  v = readsrc(b3, fi - sB3, bf);
        else if (fi < sB4)  v = readsrc(W4, fi - sW4, bf);
        else if (fi < sCP)  v = readsrc(b4, fi - sB4, bf);
        else if (fi < sDC)  v = readsrc(cp, fi - sCP, bf);
        else                v = readsrc(dc, fi - sDC, bf);
        ((float*)wsb)[F32_BASE + fi] = v;
    }
}

union Frag { uint4 u4; uint2 u2[2]; uint32_t u[4]; short8 s8; uint16_t h[8]; };

// 32x32x16 transposed-MFMA chain with zero-shuffle layer handoff (round 9,
// 76 us). Round-11 single change: silu2bf pair via ext_vector C ops +
// shared-rcp (no asm). All weights in LDS (48 KB single buffer, imm-offset
// ds_read_b128); biases folded into MFMA C-in. 512 thr = 8 waves x 32 rows =
// 256 rows/block, grid 512; LDS 55.5 KB.
__global__ __launch_bounds__(512, 4)
void chambers_mfma(const void* __restrict__ resv, const uint16_t* __restrict__ wsb,
                   const uint32_t* __restrict__ cpw, float* __restrict__ outF) {
    const float* wsf = (const float*)wsb;
    const bool bfin = (cpw[0] != 0u);
    const int tid = threadIdx.x;
    const int w = tid >> 6, l = tid & 63;
    const int l5 = l & 31, q2 = l >> 5;
    const int row = blockIdx.x * 256 + w * 32 + l5;

    __shared__ __align__(16) uint16_t sW[CH_U16];  // 48 KB: F1+F2+F3, one chamber
    __shared__ __align__(16) float sB[NSMALL];     // 6336 B biases/consts

#define STAGE(CC)                                                              \
    {                                                                          \
        const uint16_t* gsrc = wsb + (CC) * CH_U16;                            \
        _Pragma("unroll")                                                      \
        for (int rr = 0; rr < 6; ++rr) {                                       \
            const int i = rr * 8 + w;              /* chunk 0..47, 1 KB */     \
            __builtin_amdgcn_global_load_lds(                                  \
                (const GLB_AS uint32_t*)(gsrc + i * 512 + l * 8),              \
                (LDS_AS uint32_t*)(sW + i * 512), 16, 0, 0);                   \
        }                                                                      \
    }

    STAGE(0)
    for (int i = tid; i < NSMALL; i += 512) sB[i] = wsf[F32_BASE + i];

    // ===== res row fragments (B operand): k = kb*16 + q2*8 + e, K 100->112 =====
    Frag R[7];
    if (bfin) {
        const uint16_t* bp = (const uint16_t*)resv + (size_t)row * 100;
#pragma unroll
        for (int kb = 0; kb < 6; ++kb) {
            const int k0 = kb * 16 + q2 * 8;
            R[kb].u2[0] = *(const uint2*)(bp + k0);
            R[kb].u2[1] = *(const uint2*)(bp + k0 + 4);
        }
        R[6].u4 = make_uint4(0, 0, 0, 0);
        if (q2 == 0) R[6].u2[0] = *(const uint2*)(bp + 96);
    } else {
        const float* fp = (const float*)resv + (size_t)row * 100;
#pragma unroll
        for (int kb = 0; kb < 6; ++kb) {
            const int k0 = kb * 16 + q2 * 8;
            float4 x0 = *(const float4*)(fp + k0);
            float4 x1 = *(const float4*)(fp + k0 + 4);
            R[kb].u[0] = cvtpk_bf16(x0.x, x0.y);
            R[kb].u[1] = cvtpk_bf16(x0.z, x0.w);
            R[kb].u[2] = cvtpk_bf16(x1.x, x1.y);
            R[kb].u[3] = cvtpk_bf16(x1.z, x1.w);
        }
        R[6].u4 = make_uint4(0, 0, 0, 0);
        if (q2 == 0) {
            float4 x0 = *(const float4*)(fp + 96);
            R[6].u[0] = cvtpk_bf16(x0.x, x0.y);
            R[6].u[1] = cvtpk_bf16(x0.z, x0.w);
        }
    }

    __syncthreads();               // stage 0 + sB visible

    float raw0 = 0.f, raw1 = 0.f, raw2 = 0.f, raw3 = 0.f, raw4 = 0.f, raw5 = 0.f;
    Frag pk1f[2][4];               // H1: [j][ct], u[ar] — static-indexed
    Frag pk2f[2][2];               // H2: [j][ct2]

#pragma unroll 1
    for (int c = 0; c < 6; ++c) {
        // ===== L1: H1^T = W1 . res^T  (4 col-tiles of 32, K=112) =====
#pragma unroll
        for (int ct = 0; ct < 4; ++ct) {
            float16v acc;
#pragma unroll
            for (int ar = 0; ar < 4; ++ar) {           // bias-fold: C-in = b1
                const float4 bv = *(const float4*)(sB + sB1 + c * 128 + ct * 32 + ar * 8 + q2 * 4);
                acc[4 * ar + 0] = bv.x; acc[4 * ar + 1] = bv.y;
                acc[4 * ar + 2] = bv.z; acc[4 * ar + 3] = bv.w;
            }
            const uint16_t* fp1 = sW + (ct * 7) * 512 + l * 8;
#pragma unroll
            for (int kb = 0; kb < 7; ++kb) {
                Frag Af; Af.u4 = *(const uint4*)(fp1 + kb * 512);
                acc = __builtin_amdgcn_mfma_f32_32x32x16_bf16(Af.s8, R[kb].s8, acc, 0, 0, 0);
            }
#pragma unroll
            for (int ar = 0; ar < 4; ++ar) {
                pk1f[0][ct].u[ar] = silu2bf(acc[4 * ar + 0], acc[4 * ar + 1]);
                pk1f[1][ct].u[ar] = silu2bf(acc[4 * ar + 2], acc[4 * ar + 3]);
            }
        }

        // ===== L2: H2^T = W2 . H1^T  (2 col-tiles, K=128; zero-shuffle B) =====
#pragma unroll
        for (int ct2 = 0; ct2 < 2; ++ct2) {
            float16v acc;
#pragma unroll
            for (int ar = 0; ar < 4; ++ar) {           // bias-fold: C-in = b2
                const float4 bv = *(const float4*)(sB + sB2 + c * 64 + ct2 * 32 + ar * 8 + q2 * 4);
                acc[4 * ar + 0] = bv.x; acc[4 * ar + 1] = bv.y;
                acc[4 * ar + 2] = bv.z; acc[4 * ar + 3] = bv.w;
            }
            const uint16_t* fp2 = sW + oF2 + (ct2 * 8) * 512 + l * 8;
#pragma unroll
            for (int kb = 0; kb < 8; ++kb) {
                Frag Af; Af.u4 = *(const uint4*)(fp2 + kb * 512);
                acc = __builtin_amdgcn_mfma_f32_32x32x16_bf16(Af.s8, pk1f[kb & 1][kb >> 1].s8, acc, 0, 0, 0);
            }
#pragma unroll
            for (int ar = 0; ar < 4; ++ar) {
                pk2f[0][ct2].u[ar] = silu2bf(acc[4 * ar + 0], acc[4 * ar + 1]);
                pk2f[1][ct2].u[ar] = silu2bf(acc[4 * ar + 2], acc[4 * ar + 3]);
            }
        }

        // ===== L3: H3^T = W3 . H2^T  (1 col-tile of 32, K=64; zero-shuffle B) =====
        {
            float16v acc;
#pragma unroll
            for (int ar = 0; ar < 4; ++ar) {           // bias-fold: C-in = b3
                const float4 bv = *(const float4*)(sB + sB3 + c * 32 + ar * 8 + q2 * 4);
                acc[4 * ar + 0] = bv.x; acc[4 * ar + 1] = bv.y;
                acc[4 * ar + 2] = bv.z; acc[4 * ar + 3] = bv.w;
            }
            const uint16_t* fp3 = sW + oF3 + l * 8;
#pragma unroll
            for (int kb = 0; kb < 4; ++kb) {
                Frag Af; Af.u4 = *(const uint4*)(fp3 + kb * 512);
                acc = __builtin_amdgcn_mfma_f32_32x32x16_bf16(Af.s8, pk2f[kb & 1][kb >> 1].s8, acc, 0, 0, 0);
            }
            // ===== L4: raw[r=l5] = silu(H3).W4 + b4, reduce over q2 (frozen r9) =====
            float part = 0.f;
#pragma unroll
            for (int ar = 0; ar < 4; ++ar) {
                const float4 wv = *(const float4*)(sB + sW4 + c * 32 + ar * 8 + q2 * 4);
                part = fmaf(siluf(acc[4 * ar + 0]), wv.x, part);
                part = fmaf(siluf(acc[4 * ar + 1]), wv.y, part);
                part = fmaf(siluf(acc[4 * ar + 2]), wv.z, part);
                part = fmaf(siluf(acc[4 * ar + 3]), wv.w, part);
            }
            part += __shfl_xor(part, 32);
            const float rv = part + sB[sB4 + c];
            raw0 = (c == 0) ? rv : raw0;
            raw1 = (c == 1) ? rv : raw1;
            raw2 = (c == 2) ? rv : raw2;
            raw3 = (c == 3) ? rv : raw3;
            raw4 = (c == 4) ? rv : raw4;
            raw5 = (c == 5) ? rv : raw5;
        }

        if (c < 5) {
            __syncthreads();               // all waves done reading sW (chamber c)
            STAGE(c + 1)
            __syncthreads();               // chamber c+1 staged
        }
    }

    // ===== Coupling fixed point (redundant over q2; frozen r9) =====
    const float rv6[6] = {raw0, raw1, raw2, raw3, raw4, raw5};
    float av[6];
#pragma unroll
    for (int c = 0; c < 6; ++c) av[c] = sigmoidf_fast(rv6[c]);
    const float K = 0.02f;
#pragma unroll 1
    for (int it = 0; it < 5; ++it) {
        float tt[6];
#pragma unroll
        for (int i = 0; i < 6; ++i) tt[i] = av[i] * sB[sDC + i] * K;
#pragma unroll
        for (int j = 0; j < 6; ++j) {
            float dl = 0.0f;
#pragma unroll
            for (int i = 0; i < 6; ++i) dl = fmaf(tt[i], sB[sCP + i * 6 + j], dl);
            av[j] = sigmoidf_fast(rv6[j] + dl);
        }
    }
    if (q2 == 0) {
        float2* oa = (float2*)(outF + (size_t)row * 6);
        oa[0] = make_float2(av[0], av[1]);
        oa[1] = make_float2(av[2], av[3]);
        oa[2] = make_float2(av[4], av[5]);
        float2* orw = (float2*)(outF + (size_t)B_TOTAL * 6 + (size_t)row * 6);
        orw[0] = make_float2(rv6[0], rv6[1]);
        orw[1] = make_float2(rv6[2], rv6[3]);
        orw[2] = make_float2(rv6[4], rv6[5]);
    }
#undef STAGE
}

extern "C" void kernel_launch(void* const* d_in, const int* in_sizes, int n_in,
                              void* d_out, int out_size, void* d_ws, size_t ws_size,
                              hipStream_t stream) {
    uint16_t* wsb = (uint16_t*)d_ws;
    convert_kernel<<<(CONV_TOT + 255) / 256, 256, 0, stream>>>(
        d_in[1], d_in[2], d_in[3], d_in[4], d_in[5], d_in[6], d_in[7], d_in[8],
        d_in[9], d_in[10], wsb);
    chambers_mfma<<<B_TOTAL / 256, 512, 0, stream>>>(
        d_in[0], wsb, (const uint32_t*)d_in[9], (float*)d_out);
}